// Round 9
// baseline (147.326 us; speedup 1.0000x reference)
//
#include <hip/hip_runtime.h>
#include <hip/hip_bf16.h>

// PatchEmbed MFMA v7 (persistent). f32 data (proven R1/R2).
// B=8,N=16384,M=2048,K=32,EMB=256.
//   pe_pack: W2/W3 f32 -> bf16 MFMA B-fragments in d_ws (80 KB).
//   pe_mfma: PERSISTENT grid = 1024 blocks (exactly 4/CU), each block loops
//            8 center-pairs. B2f/B3f/W1/b1/b3 loaded ONCE per block (was per
//            center-pair: ~48 loads x 8192 blocks of pure prologue).
// History: R5 (256,6) cap -> B-frag spill, 2.4x slower: keep (256,4).
//          R8 streamed B3f from global -> stage-3 vmcnt serialization, 68us:
//          keep B3f register-resident.
// Data path identical to R7 (passed, absmax 0.125): swapped stage-2 MFMA
// (h2^T = W2*h1^T) -> uint2 LDS writes in stage-3 A layout; stage-3 folds
// rt-pairs in C-regs then 2 shfl_xor for max-over-K.

typedef __attribute__((ext_vector_type(8))) short bf16x8;
typedef __attribute__((ext_vector_type(4))) float f32x4v;

constexpr int Bn = 8, Nn = 16384, Mn = 2048, Kn = 32, EMB = 256;
constexpr int G = 2;               // centers per iteration
constexpr int ROWS = G * Kn;       // 64 rows per iteration
constexpr int GRID = 1024;         // 4 blocks per CU, exactly
constexpr int ITERS = (Bn * Mn) / G / GRID;   // 8

__device__ __forceinline__ unsigned pk2(float a, float b) {  // v_cvt_pk_bf16_f32
    float2 f; f.x = a; f.y = b;
    __hip_bfloat162 h = __float22bfloat162_rn(f);
    return *(unsigned*)&h;
}

__device__ __forceinline__ bf16x8 pack8(const float* v) {
    unsigned u0 = pk2(v[0], v[1]), u1 = pk2(v[2], v[3]);
    unsigned u2 = pk2(v[4], v[5]), u3 = pk2(v[6], v[7]);
    uint4 u = make_uint4(u0, u1, u2, u3);
    return *(bf16x8*)&u;
}

// ---- kernel A: pack W2 (1024 frags) + W3 (4096 frags) into ws ----
__global__ __launch_bounds__(256) void pe_pack(
    const float* __restrict__ W2, const float* __restrict__ W3,
    uint4* __restrict__ ws)
{
    int gid = blockIdx.x * 256 + threadIdx.x;
    if (gid < 1024) {
        int e = gid, l = e & 63;
        int kt = (e >> 6) & 1, ct = (e >> 7) & 1, w = e >> 8;
        int q = l >> 4, n = l & 15;
        int ch = w * 32 + ct * 16 + n;
        const float* p = W2 + ch * 64 + kt * 32 + q * 8;
        float t[8];
        *(float4*)&t[0] = *(const float4*)p;
        *(float4*)&t[4] = *(const float4*)(p + 4);
        bf16x8 v = pack8(t);
        ws[e] = *(uint4*)&v;
    } else if (gid < 5120) {
        int e = gid - 1024, l = e & 63;
        int kt = (e >> 6) & 3, ct = (e >> 8) & 3, w = e >> 10;
        int q = l >> 4, n = l & 15;
        int ch = w * 64 + ct * 16 + n;
        const float* p = W3 + ch * 128 + kt * 32 + q * 8;
        float t[8];
        *(float4*)&t[0] = *(const float4*)p;
        *(float4*)&t[4] = *(const float4*)(p + 4);
        bf16x8 v = pack8(t);
        ws[1024 + e] = *(uint4*)&v;
    }
}

__global__ __launch_bounds__(256, 4) void pe_mfma(
    const float* __restrict__ xyz,      // (B,N,3)
    const float* __restrict__ centers,  // (B,M,3)
    const int*   __restrict__ idx,      // (B,M,K)
    const float* __restrict__ W1,       // (64,3)
    const float* __restrict__ b1,       // (64,)
    const float* __restrict__ b2,       // (128,)
    const float* __restrict__ b3,       // (256,)
    const uint4* __restrict__ wsf,      // packed W2/W3 fragments
    float*       __restrict__ out)      // (B,M,256)
{
    __shared__ uint4 h1v[ROWS * 64 * 2 / 16];    // 512 uint4  = 8 KB
    __shared__ uint4 h2v[ROWS * 128 * 2 / 16];   // 1024 uint4 = 16 KB

    const int tid = threadIdx.x;
    const int w   = tid >> 6;          // wave 0..3
    const int l   = tid & 63;
    const int q   = l >> 4;            // quad 0..3
    const int n   = l & 15;            // frag row/col index

    // ================= per-block prologue (hoisted out of the loop) =======
    bf16x8 B2f[2][2];
    float4 bb2[2];
    const int ch0 = w * 32 + q * 4;
    #pragma unroll
    for (int ct = 0; ct < 2; ++ct) {
        bb2[ct] = *(const float4*)&b2[ch0 + ct * 16];
        #pragma unroll
        for (int kt = 0; kt < 2; ++kt) {
            uint4 u = wsf[((w * 2 + ct) * 2 + kt) * 64 + l];
            B2f[ct][kt] = *(bf16x8*)&u;
        }
    }
    bf16x8 B3f[4][4];  float b3v[4];
    #pragma unroll
    for (int ct = 0; ct < 4; ++ct) {
        b3v[ct] = b3[w * 64 + ct * 16 + n];
        #pragma unroll
        for (int kt = 0; kt < 4; ++kt) {
            uint4 u = wsf[1024 + ((w * 4 + ct) * 4 + kt) * 64 + l];
            B3f[ct][kt] = *(bf16x8*)&u;
        }
    }
    // W1/b1 wave-uniform scalars (s_loads), once per block
    const int o4b = __builtin_amdgcn_readfirstlane((tid >> 6) * 4);
    float4 W1a[4], W1b[4], W1w[4], b1c[4];
    #pragma unroll
    for (int i = 0; i < 4; ++i) {
        const float4* Wp = (const float4*)(W1 + (o4b + i) * 12);
        W1a[i] = Wp[0]; W1b[i] = Wp[1]; W1w[i] = Wp[2];
        b1c[i] = *(const float4*)(b1 + (o4b + i) * 4);
    }

    const int r64 = tid & 63;                     // row 0..63
    const int T = r64 >> 4, rr = r64 & 15, j0 = (tid >> 6) * 2;

    // ================= persistent loop over center-pairs ==================
    #pragma unroll 1
    for (int it = 0; it < ITERS; ++it) {
        const int bm0 = (blockIdx.x + it * GRID) * G;

        // ---- gather + center-subtract (4 threads per row, redundant) ----
        int bm = bm0 + (r64 >> 5);
        int bb = bm >> 11;
        int id = idx[(size_t)bm * Kn + (r64 & 31)];
        const float* p = xyz + ((size_t)bb * Nn + id) * 3;
        const float* c = centers + (size_t)bm * 3;
        float lx = p[0] - c[0], ly = p[1] - c[1], lz = p[2] - c[2];

        // ---- stage 1: 16 channels of this thread's row ----
        {
            float h[16];
            #pragma unroll
            for (int i = 0; i < 4; ++i) {
                h[4*i+0] = fmaxf(b1c[i].x + lx*W1a[i].x + ly*W1a[i].y + lz*W1a[i].z, 0.f);
                h[4*i+1] = fmaxf(b1c[i].y + lx*W1a[i].w + ly*W1b[i].x + lz*W1b[i].y, 0.f);
                h[4*i+2] = fmaxf(b1c[i].z + lx*W1b[i].z + ly*W1b[i].w + lz*W1w[i].x, 0.f);
                h[4*i+3] = fmaxf(b1c[i].w + lx*W1w[i].y + ly*W1w[i].z + lz*W1w[i].w, 0.f);
            }
            #pragma unroll
            for (int jj = 0; jj < 2; ++jj) {
                bf16x8 v = pack8(&h[8 * jj]);
                h1v[T * 128 + (j0 + jj) * 16 + rr] = *(uint4*)&v;
            }
        }
        __syncthreads();

        // ---- stage 2: h2^T = W2*h1^T (+b2, relu) -> uint2 LDS writes ----
        {
            ushort* h2s = (ushort*)h2v;
            #pragma unroll
            for (int rt = 0; rt < G * 2; ++rt) {
                uint4 a0u = h1v[rt * 128 + q * 16 + n];
                uint4 a1u = h1v[rt * 128 + (4 + q) * 16 + n];
                bf16x8 A0 = *(bf16x8*)&a0u, A1 = *(bf16x8*)&a1u;
                #pragma unroll
                for (int ct = 0; ct < 2; ++ct) {
                    int ch = ch0 + ct * 16;
                    f32x4v c0 = {0.f, 0.f, 0.f, 0.f};
                    c0 = __builtin_amdgcn_mfma_f32_16x16x32_bf16(B2f[ct][0], A0, c0, 0, 0, 0);
                    c0 = __builtin_amdgcn_mfma_f32_16x16x32_bf16(B2f[ct][1], A1, c0, 0, 0, 0);
                    unsigned p0 = pk2(fmaxf(c0[0] + bb2[ct].x, 0.f),
                                      fmaxf(c0[1] + bb2[ct].y, 0.f));
                    unsigned p1 = pk2(fmaxf(c0[2] + bb2[ct].z, 0.f),
                                      fmaxf(c0[3] + bb2[ct].w, 0.f));
                    uint2 pk; pk.x = p0; pk.y = p1;
                    *(uint2*)&h2s[rt * 2048 + (ch >> 3) * 128 + n * 8 + (ch & 7)] = pk;
                }
            }
        }
        __syncthreads();

        // ---- stage 3: wave owns 64 cols; fold rt-pairs, 2 shfls, store ----
        {
            #pragma unroll
            for (int g = 0; g < G; ++g) {
                bf16x8 Ae[4], Ao[4];
                #pragma unroll
                for (int kt = 0; kt < 4; ++kt) {
                    uint4 ae = h2v[(2*g)   * 256 + (kt * 4 + q) * 16 + n];
                    uint4 ao = h2v[(2*g+1) * 256 + (kt * 4 + q) * 16 + n];
                    Ae[kt] = *(bf16x8*)&ae;
                    Ao[kt] = *(bf16x8*)&ao;
                }
                #pragma unroll
                for (int ct = 0; ct < 4; ++ct) {
                    f32x4v Ce = {0.f, 0.f, 0.f, 0.f};
                    f32x4v Co = {0.f, 0.f, 0.f, 0.f};
                    #pragma unroll
                    for (int kt = 0; kt < 4; ++kt) {
                        Ce = __builtin_amdgcn_mfma_f32_16x16x32_bf16(Ae[kt], B3f[ct][kt], Ce, 0, 0, 0);
                        Co = __builtin_amdgcn_mfma_f32_16x16x32_bf16(Ao[kt], B3f[ct][kt], Co, 0, 0, 0);
                    }
                    float v = fmaxf(fmaxf(fmaxf(Ce[0], Co[0]), fmaxf(Ce[1], Co[1])),
                                    fmaxf(fmaxf(Ce[2], Co[2]), fmaxf(Ce[3], Co[3])));
                    v = fmaxf(v, __shfl_xor(v, 16));
                    v = fmaxf(v, __shfl_xor(v, 32));
                    if (q == 0) {
                        out[(size_t)(bm0 + g) * EMB + w * 64 + ct * 16 + n] = v + b3v[ct];
                    }
                }
            }
        }
        // no extra barrier needed: next iter's h2v writes are fenced by the
        // barrier after stage 1, and h1v writes don't conflict with stage-3
        // h2v reads.
    }
}

extern "C" void kernel_launch(void* const* d_in, const int* in_sizes, int n_in,
                              void* d_out, int out_size, void* d_ws, size_t ws_size,
                              hipStream_t stream) {
    const float* xyz     = (const float*)d_in[0];
    const float* centers = (const float*)d_in[1];
    const int*   idx     = (const int*)  d_in[2];
    const float* W1      = (const float*)d_in[3];
    const float* b1      = (const float*)d_in[4];
    const float* W2      = (const float*)d_in[5];
    const float* b2      = (const float*)d_in[6];
    const float* W3      = (const float*)d_in[7];
    const float* b3      = (const float*)d_in[8];
    float*       out     = (float*)d_out;
    uint4*       ws      = (uint4*)d_ws;    // needs 5120*16 = 80 KB

    pe_pack<<<20, 256, 0, stream>>>(W2, W3, ws);
    pe_mfma<<<GRID, 256, 0, stream>>>(
        xyz, centers, idx, W1, b1, b2, b3, ws, out);
}

// Round 10
// 122.177 us; speedup vs baseline: 1.2058x; 1.2058x over previous
//
#include <hip/hip_runtime.h>
#include <hip/hip_bf16.h>

// PatchEmbed MFMA v8. f32 data (proven R1/R2). B=8,N=16384,M=2048,K=32,EMB=256.
// Structure = R7 (best, 56us): 8192 one-shot blocks, G=2 centers/block,
// 256 thr, LDS 24KB, (256,4) bounds, pe_pack pre-packs weights into d_ws.
// v8 change: stages 2+3 use v_mfma_f32_32x32x16_bf16 (40 MFMA/wave vs 80,
// -50% issue slots, -17% MFMA cycles; shfl 16->4; coalesced 1-float stores).
// History locked in: R5 tighter launch_bounds -> spill (keep 256,4);
// R8 streamed B3 -> vmcnt serialization (keep B3 register-resident);
// R9 persistent grid -> phase convoy + L2 locality loss (keep short blocks).
// Layouts (32x32x16): A[m][k]: m=l&31, k=(l>>5)*8+j;  B[k][n]: n=l&31,
// k=(l>>5)*8+j;  C/D: n=l&31, m=(reg&3)+8*(reg>>2)+4*(l>>5)  [m74/m101].

typedef __attribute__((ext_vector_type(8)))  short bf16x8;
typedef __attribute__((ext_vector_type(16))) float f32x16;

constexpr int Bn = 8, Nn = 16384, Mn = 2048, Kn = 32, EMB = 256;
constexpr int G = 2;               // centers per block
constexpr int ROWS = G * Kn;       // 64 rows per block

__device__ __forceinline__ unsigned pk2(float a, float b) {  // v_cvt_pk_bf16_f32
    float2 f; f.x = a; f.y = b;
    __hip_bfloat162 h = __float22bfloat162_rn(f);
    return *(unsigned*)&h;
}

__device__ __forceinline__ bf16x8 pack8(const float* v) {
    unsigned u0 = pk2(v[0], v[1]), u1 = pk2(v[2], v[3]);
    unsigned u2 = pk2(v[4], v[5]), u3 = pk2(v[6], v[7]);
    uint4 u = make_uint4(u0, u1, u2, u3);
    return *(bf16x8*)&u;
}

// ---- pe_pack: W2 -> stage-2 A-frags (1024 uint4), W3 -> stage-3 B-frags
//      (4096 uint4 at +1024). 32x32x16 layouts. ----
__global__ __launch_bounds__(256) void pe_pack(
    const float* __restrict__ W2, const float* __restrict__ W3,
    uint4* __restrict__ ws)
{
    int gid = blockIdx.x * 256 + threadIdx.x;
    if (gid < 1024) {
        // A-frag: A[m=ch][k]: ch = mt*32+(l&31), k = kt*16+(l>>5)*8+j
        int e = gid, l = e & 63;
        int kt = (e >> 6) & 3, mt = e >> 8;        // mt 0..3
        const float* p = W2 + (mt * 32 + (l & 31)) * 64 + kt * 16 + (l >> 5) * 8;
        float t[8];
        *(float4*)&t[0] = *(const float4*)p;
        *(float4*)&t[4] = *(const float4*)(p + 4);
        bf16x8 v = pack8(t);
        ws[e] = *(uint4*)&v;
    } else if (gid < 5120) {
        // B-frag: B[k][n=outch]: n = nt*32+(l&31), k = kk*16+(l>>5)*8+j
        int e = gid - 1024, l = e & 63;
        int kk = (e >> 6) & 7, nt = e >> 9;        // nt 0..7
        const float* p = W3 + (nt * 32 + (l & 31)) * 128 + kk * 16 + (l >> 5) * 8;
        float t[8];
        *(float4*)&t[0] = *(const float4*)p;
        *(float4*)&t[4] = *(const float4*)(p + 4);
        bf16x8 v = pack8(t);
        ws[1024 + e] = *(uint4*)&v;
    }
}

__global__ __launch_bounds__(256, 4) void pe_mfma(
    const float* __restrict__ xyz,      // (B,N,3)
    const float* __restrict__ centers,  // (B,M,3)
    const int*   __restrict__ idx,      // (B,M,K)
    const float* __restrict__ W1,       // (64,3)
    const float* __restrict__ b1,       // (64,)
    const float* __restrict__ b2,       // (128,)
    const float* __restrict__ b3,       // (256,)
    const uint4* __restrict__ wsf,      // packed W2/W3 fragments
    float*       __restrict__ out)      // (B,M,256)
{
    // h1v slot (rt2, kt, l): h1[row = rt2*32+(l&31)][ch = kt*16+(l>>5)*8+j]
    __shared__ uint4 h1v[2 * 4 * 64];    // 512 uint4  = 8 KB
    // h2v slot (rt2, kk, l): h2[row = rt2*32+(l&31)][ch = kk*16+(l>>5)*8+j]
    __shared__ uint4 h2v[2 * 8 * 64];    // 1024 uint4 = 16 KB

    const int tid = threadIdx.x;
    const int w   = tid >> 6;          // wave 0..3
    const int l   = tid & 63;
    const int hl  = l >> 5;            // lane half
    const int bm0 = blockIdx.x * G;

    // ---- per-block fragment prologue ----
    bf16x8 A2[4];                      // stage-2 A (W2, ch-tile = w)
    #pragma unroll
    for (int kt = 0; kt < 4; ++kt) {
        uint4 u = wsf[(w * 4 + kt) * 64 + l];
        A2[kt] = *(bf16x8*)&u;
    }
    bf16x8 B3[2][8];                   // stage-3 B (W3, col-tiles w, w+4)
    float  b3v[2];
    #pragma unroll
    for (int c2 = 0; c2 < 2; ++c2) {
        int nt = w + 4 * c2;
        b3v[c2] = b3[nt * 32 + (l & 31)];
        #pragma unroll
        for (int kk = 0; kk < 8; ++kk) {
            uint4 u = wsf[1024 + (nt * 8 + kk) * 64 + l];
            B3[c2][kk] = *(bf16x8*)&u;
        }
    }
    float4 bb2[4];                     // stage-2 bias, C-layout-matched
    #pragma unroll
    for (int t = 0; t < 4; ++t)
        bb2[t] = *(const float4*)&b2[32 * w + 8 * t + 4 * hl];

    // W1/b1 wave-uniform scalars
    const int o4b = __builtin_amdgcn_readfirstlane(w * 4);
    float4 W1a[4], W1b[4], W1w[4], b1c[4];
    #pragma unroll
    for (int i = 0; i < 4; ++i) {
        const float4* Wp = (const float4*)(W1 + (o4b + i) * 12);
        W1a[i] = Wp[0]; W1b[i] = Wp[1]; W1w[i] = Wp[2];
        b1c[i] = *(const float4*)(b1 + (o4b + i) * 4);
    }

    // ---- gather + center-subtract (4 waves redundant over 64 rows) ----
    const int r = l;                   // row 0..63 (this wave's copy)
    {
        int bm = bm0 + (r >> 5);
        int bb = bm >> 11;
        int id = idx[(size_t)bm * Kn + (r & 31)];
        const float* p = xyz + ((size_t)bb * Nn + id) * 3;
        const float* c = centers + (size_t)bm * 3;
        float lx = p[0] - c[0], ly = p[1] - c[1], lz = p[2] - c[2];

        // ---- stage 1: this thread computes h1[row r][ch 16w .. 16w+15] ----
        float h[16];
        #pragma unroll
        for (int i = 0; i < 4; ++i) {
            h[4*i+0] = fmaxf(b1c[i].x + lx*W1a[i].x + ly*W1a[i].y + lz*W1a[i].z, 0.f);
            h[4*i+1] = fmaxf(b1c[i].y + lx*W1a[i].w + ly*W1b[i].x + lz*W1b[i].y, 0.f);
            h[4*i+2] = fmaxf(b1c[i].z + lx*W1b[i].z + ly*W1b[i].w + lz*W1w[i].x, 0.f);
            h[4*i+3] = fmaxf(b1c[i].w + lx*W1w[i].y + ly*W1w[i].z + lz*W1w[i].w, 0.f);
        }
        // write to h1v: kt = w (chs 16w..16w+15 = one 16-k step), two halves
        #pragma unroll
        for (int hh = 0; hh < 2; ++hh) {
            bf16x8 v = pack8(&h[8 * hh]);
            h1v[((r >> 5) * 4 + w) * 64 + (r & 31) + 32 * hh] = *(uint4*)&v;
        }
    }
    __syncthreads();

    // ---- stage 2: h2^T = W2 * h1^T (+b2, relu); 32x32x16; wave = ch-tile w
    {
        #pragma unroll
        for (int rt2 = 0; rt2 < 2; ++rt2) {
            f32x16 C;
            #pragma unroll
            for (int i = 0; i < 16; ++i) C[i] = 0.f;
            #pragma unroll
            for (int kt = 0; kt < 4; ++kt) {
                uint4 u = h1v[(rt2 * 4 + kt) * 64 + l];
                C = __builtin_amdgcn_mfma_f32_32x32x16_bf16(A2[kt], *(bf16x8*)&u, C, 0, 0, 0);
            }
            // C[reg]: ch = 32w + (reg&3) + 8*(reg>>2) + 4*hl, row = rt2*32+(l&31)
            #pragma unroll
            for (int t = 0; t < 4; ++t) {
                unsigned p0 = pk2(fmaxf(C[4*t+0] + bb2[t].x, 0.f),
                                  fmaxf(C[4*t+1] + bb2[t].y, 0.f));
                unsigned p1 = pk2(fmaxf(C[4*t+2] + bb2[t].z, 0.f),
                                  fmaxf(C[4*t+3] + bb2[t].w, 0.f));
                uint2 pk; pk.x = p0; pk.y = p1;
                // ch = 32w+8t+4hl -> kk = 2w + (t>>1), lane_dst = (l&31)+32*(t&1),
                // ushort offset within slot = 4*hl
                ushort* dst = (ushort*)h2v
                    + (((rt2 * 8 + 2 * w + (t >> 1)) * 64 + (l & 31) + 32 * (t & 1)) * 8
                       + 4 * hl);
                *(uint2*)dst = pk;
            }
        }
    }
    __syncthreads();

    // ---- stage 3: out = max_k(h2 @ W3^T) + b3; 32x32x16; one center = one
    //      32-row tile -> reduce 16 C-regs + single shfl_xor(32) ----
    {
        #pragma unroll
        for (int rt2 = 0; rt2 < 2; ++rt2) {
            bf16x8 Af[8];
            #pragma unroll
            for (int kk = 0; kk < 8; ++kk) {
                uint4 u = h2v[(rt2 * 8 + kk) * 64 + l];
                Af[kk] = *(bf16x8*)&u;
            }
            #pragma unroll
            for (int c2 = 0; c2 < 2; ++c2) {
                f32x16 C;
                #pragma unroll
                for (int i = 0; i < 16; ++i) C[i] = 0.f;
                #pragma unroll
                for (int kk = 0; kk < 8; ++kk)
                    C = __builtin_amdgcn_mfma_f32_32x32x16_bf16(Af[kk], B3[c2][kk], C, 0, 0, 0);
                float m0 = fmaxf(fmaxf(C[0],  C[1]),  fmaxf(C[2],  C[3]));
                float m1 = fmaxf(fmaxf(C[4],  C[5]),  fmaxf(C[6],  C[7]));
                float m2 = fmaxf(fmaxf(C[8],  C[9]),  fmaxf(C[10], C[11]));
                float m3 = fmaxf(fmaxf(C[12], C[13]), fmaxf(C[14], C[15]));
                float v  = fmaxf(fmaxf(m0, m1), fmaxf(m2, m3));
                v = fmaxf(v, __shfl_xor(v, 32));
                if (l < 32) {
                    int nt = w + 4 * c2;
                    out[(size_t)(bm0 + rt2) * EMB + nt * 32 + l] = v + b3v[c2];
                }
            }
        }
    }
}

extern "C" void kernel_launch(void* const* d_in, const int* in_sizes, int n_in,
                              void* d_out, int out_size, void* d_ws, size_t ws_size,
                              hipStream_t stream) {
    const float* xyz     = (const float*)d_in[0];
    const float* centers = (const float*)d_in[1];
    const int*   idx     = (const int*)  d_in[2];
    const float* W1      = (const float*)d_in[3];
    const float* b1      = (const float*)d_in[4];
    const float* W2      = (const float*)d_in[5];
    const float* b2      = (const float*)d_in[6];
    const float* W3      = (const float*)d_in[7];
    const float* b3      = (const float*)d_in[8];
    float*       out     = (float*)d_out;
    uint4*       ws      = (uint4*)d_ws;    // needs 5120*16 = 80 KB

    pe_pack<<<20, 256, 0, stream>>>(W2, W3, ws);
    pe_mfma<<<(Bn * Mn) / G, 256, 0, stream>>>(
        xyz, centers, idx, W1, b1, b2, b3, ws, out);
}